// Round 4
// baseline (124.781 us; speedup 1.0000x reference)
//
#include <hip/hip_runtime.h>

#define BB 8
#define CC 64
#define UU 3
#define NN 512
#define POS (UU * NN)               // 1536
#define QKV_ELEMS (BB * CC * POS)   // 786432 floats per tensor
// 0.125 (= C^-0.5) * log2(e), folded into q so softmax uses raw exp2
#define SCALE2 0.1803368801111793f

// ---------------- Kernel 1: projection (q,k,v) into workspace --------------
// DD=8 output channels per block: x traffic = 6.3MB * 64/8 = 50 MB (L2-bound).
// grid = 8 b * 8 dgroups * 6 chunks = 384 blocks, 256 threads.
__global__ __launch_bounds__(256) void proj_kernel(
    const float* __restrict__ x,
    const float* __restrict__ Wq,
    const float* __restrict__ Wk,
    const float* __restrict__ Wv,
    float* __restrict__ ws)
{
    const int blk   = blockIdx.x;          // 0..383
    const int bg    = blk / 6;             // 0..63 : (b, dgroup)
    const int chunk = blk % 6;
    const int b     = bg >> 3;
    const int d0    = (bg & 7) * 8;
    const int tid   = threadIdx.x;
    const int p     = chunk * 256 + tid;   // 0..1535

    __shared__ float w[24][CC];            // rows 0-7: q, 8-15: k, 16-23: v
    for (int t = tid; t < 24 * CC; t += 256) {
        int r = t >> 6, c = t & 63;
        const float* W = (r < 8) ? Wq : (r < 16) ? Wk : Wv;
        w[r][c] = W[(d0 + (r & 7)) * CC + c];
    }
    __syncthreads();

    const float* xb = x + (size_t)b * CC * POS + p;
    float qa[8], ka[8], va[8];
    #pragma unroll
    for (int r = 0; r < 8; ++r) { qa[r] = 0.f; ka[r] = 0.f; va[r] = 0.f; }

    for (int c = 0; c < CC; ++c) {
        float xv = xb[c * POS];
        #pragma unroll
        for (int r = 0; r < 8; ++r) {
            qa[r] = fmaf(xv, w[r][c],      qa[r]);
            ka[r] = fmaf(xv, w[8 + r][c],  ka[r]);
            va[r] = fmaf(xv, w[16 + r][c], va[r]);
        }
    }

    float* qs = ws;
    float* ks = ws + QKV_ELEMS;
    float* vs = ws + 2 * QKV_ELEMS;
    #pragma unroll
    for (int r = 0; r < 8; ++r) {
        size_t base = (size_t)(b * CC + d0 + r) * POS + p;
        qs[base] = qa[r] * SCALE2;
        ks[base] = ka[r];
        vs[base] = va[r];
    }
}

// ---------------- Kernel 2: fused attention + residual ---------------------
// No LDS. K/V reads are wave-uniform -> compiler scalarizes to s_load_dwordx4;
// SGPR operands broadcast to all 64 lanes for free. VALU-bound by design.
// grid = BB*CC*2 = 1024 blocks; block handles (b,d) and 256 of the 512 rows.
__global__ __launch_bounds__(256) void attn_kernel(
    const float* __restrict__ x,
    const float* __restrict__ ws,
    float* __restrict__ out)
{
    const int blk  = blockIdx.x;   // 0..1023
    const int bd   = blk >> 1;     // 0..511
    const int half = blk & 1;
    const int tid  = threadIdx.x;
    const int i    = half * 256 + tid;

    const float*  qsg = ws + (size_t)bd * POS;
    const float4* k0p = (const float4*)(ws + QKV_ELEMS     + (size_t)bd * POS);
    const float4* k1p = k0p + (NN / 4);
    const float4* k2p = k0p + 2 * (NN / 4);
    const float4* v0p = (const float4*)(ws + 2 * QKV_ELEMS + (size_t)bd * POS);
    const float4* v1p = v0p + (NN / 4);
    const float4* v2p = v0p + 2 * (NN / 4);

    const float q0 = qsg[i];            // already * C^-0.5 * log2(e)
    const float q1 = qsg[NN + i];
    const float q2 = qsg[2 * NN + i];

    float l = 0.f, a0 = 0.f, a1 = 0.f, a2 = 0.f;
    #pragma unroll 2
    for (int j4 = 0; j4 < NN / 4; ++j4) {
        float4 k0 = k0p[j4];            // uniform -> s_load_dwordx4
        float4 k1 = k1p[j4];
        float4 k2 = k2p[j4];
        float4 v0 = v0p[j4];
        float4 v1 = v1p[j4];
        float4 v2 = v2p[j4];

        float s0 = fmaf(q0, k0.x, fmaf(q1, k1.x, q2 * k2.x));
        float s1 = fmaf(q0, k0.y, fmaf(q1, k1.y, q2 * k2.y));
        float s2 = fmaf(q0, k0.z, fmaf(q1, k1.z, q2 * k2.z));
        float s3 = fmaf(q0, k0.w, fmaf(q1, k1.w, q2 * k2.w));

        float p0 = __builtin_amdgcn_exp2f(s0);
        float p1 = __builtin_amdgcn_exp2f(s1);
        float p2 = __builtin_amdgcn_exp2f(s2);
        float p3 = __builtin_amdgcn_exp2f(s3);

        l += (p0 + p1) + (p2 + p3);
        a0 = fmaf(p0, v0.x, fmaf(p1, v0.y, fmaf(p2, v0.z, fmaf(p3, v0.w, a0))));
        a1 = fmaf(p0, v1.x, fmaf(p1, v1.y, fmaf(p2, v1.z, fmaf(p3, v1.w, a1))));
        a2 = fmaf(p0, v2.x, fmaf(p1, v2.y, fmaf(p2, v2.z, fmaf(p3, v2.w, a2))));
    }

    float inv = 1.0f / l;
    const float* xd = x   + (size_t)bd * POS;
    float*       od = out + (size_t)bd * POS;
    od[i]          = xd[i]          + a0 * inv;
    od[NN + i]     = xd[NN + i]     + a1 * inv;
    od[2 * NN + i] = xd[2 * NN + i] + a2 * inv;
}

// ---------------- Fallback: fused kernel (if ws too small) -----------------
__global__ __launch_bounds__(256) void vn_attn_fused(
    const float* __restrict__ x,
    const float* __restrict__ Wq,
    const float* __restrict__ Wk,
    const float* __restrict__ Wv,
    float* __restrict__ out)
{
    const int bd  = blockIdx.x;
    const int b   = bd / CC;
    const int d   = bd % CC;
    const int tid = threadIdx.x;

    __shared__ float wq[CC], wk[CC], wv[CC];
    __shared__ float qs[UU][NN];
    __shared__ float ks[UU][NN];
    __shared__ float vs[UU][NN];

    if (tid < CC) {
        wq[tid] = Wq[d * CC + tid];
        wk[tid] = Wk[d * CC + tid];
        wv[tid] = Wv[d * CC + tid];
    }
    __syncthreads();

    const float* xb = x + (size_t)b * CC * POS;
    for (int p = tid; p < POS; p += 256) {
        float qa = 0.f, ka = 0.f, va = 0.f;
        #pragma unroll 8
        for (int c = 0; c < CC; ++c) {
            float xv = xb[c * POS + p];
            qa = fmaf(xv, wq[c], qa);
            ka = fmaf(xv, wk[c], ka);
            va = fmaf(xv, wv[c], va);
        }
        int u = p >> 9, n = p & (NN - 1);
        qs[u][n] = qa * SCALE2;
        ks[u][n] = ka;
        vs[u][n] = va;
    }
    __syncthreads();

    for (int i = tid; i < NN; i += 256) {
        float q0 = qs[0][i], q1 = qs[1][i], q2 = qs[2][i];
        float l = 0.f, a0 = 0.f, a1 = 0.f, a2 = 0.f;
        for (int j = 0; j < NN; j += 4) {
            float4 k0 = *(const float4*)&ks[0][j];
            float4 k1 = *(const float4*)&ks[1][j];
            float4 k2 = *(const float4*)&ks[2][j];
            float4 v0 = *(const float4*)&vs[0][j];
            float4 v1 = *(const float4*)&vs[1][j];
            float4 v2 = *(const float4*)&vs[2][j];
            float s0 = fmaf(q0, k0.x, fmaf(q1, k1.x, q2 * k2.x));
            float s1 = fmaf(q0, k0.y, fmaf(q1, k1.y, q2 * k2.y));
            float s2 = fmaf(q0, k0.z, fmaf(q1, k1.z, q2 * k2.z));
            float s3 = fmaf(q0, k0.w, fmaf(q1, k1.w, q2 * k2.w));
            float p0 = __builtin_amdgcn_exp2f(s0);
            float p1 = __builtin_amdgcn_exp2f(s1);
            float p2 = __builtin_amdgcn_exp2f(s2);
            float p3 = __builtin_amdgcn_exp2f(s3);
            l += p0 + p1 + p2 + p3;
            a0 = fmaf(p0, v0.x, fmaf(p1, v0.y, fmaf(p2, v0.z, fmaf(p3, v0.w, a0))));
            a1 = fmaf(p0, v1.x, fmaf(p1, v1.y, fmaf(p2, v1.z, fmaf(p3, v1.w, a1))));
            a2 = fmaf(p0, v2.x, fmaf(p1, v2.y, fmaf(p2, v2.z, fmaf(p3, v2.w, a2))));
        }
        float inv = 1.0f / l;
        size_t obase = ((size_t)(b * CC + d) * UU) * NN + i;
        const float* xd = xb + (size_t)d * POS;
        out[obase]          = xd[i]          + a0 * inv;
        out[obase + NN]     = xd[NN + i]     + a1 * inv;
        out[obase + 2 * NN] = xd[2 * NN + i] + a2 * inv;
    }
}

extern "C" void kernel_launch(void* const* d_in, const int* in_sizes, int n_in,
                              void* d_out, int out_size, void* d_ws, size_t ws_size,
                              hipStream_t stream) {
    const float* x  = (const float*)d_in[0];
    const float* Wq = (const float*)d_in[1];
    const float* Wk = (const float*)d_in[2];
    const float* Wv = (const float*)d_in[3];
    float* out = (float*)d_out;

    if (ws_size >= (size_t)3 * QKV_ELEMS * sizeof(float)) {
        float* ws = (float*)d_ws;
        proj_kernel<<<dim3(8 * 8 * 6), dim3(256), 0, stream>>>(x, Wq, Wk, Wv, ws);
        attn_kernel<<<dim3(BB * CC * 2), dim3(256), 0, stream>>>(x, ws, out);
    } else {
        vn_attn_fused<<<dim3(BB * CC), dim3(256), 0, stream>>>(x, Wq, Wk, Wv, out);
    }
}